// Round 1
// baseline (51.430 us; speedup 1.0000x reference)
//
#include <hip/hip_runtime.h>

// Problem constants (from reference): B=4096, Z=128, DEG=16, E=Z*DEG=2048.
// out[b, i, j] = 1.0 everywhere except out[b, src[e], dst[e]] = beta[b, e].
// src[e] = e / DEG  (edges are row-major grouped), dst[e] random distinct per row.
//
// Fused single-pass kernel: each block owns 8 output rows (128 edges) and
// iterates over 8 batches (2 at a time). Edge weights are hoisted into
// registers once per thread (fixed edge across batches). Rows are assembled
// in LDS (init 1.0f + scatter 16 betas per row) and stored as coalesced float4.

#define ZONES 128
#define DEG   16
#define NB    8   // batches per block

__global__ __launch_bounds__(256) void fused_edge_mlp(
    const float* __restrict__ x,
    const int*   __restrict__ dst,
    const float* __restrict__ W1,
    const float* __restrict__ b1,
    const float* __restrict__ W2,
    const float* __restrict__ b2,
    const float* __restrict__ W3,
    const float* __restrict__ b3,
    float* __restrict__ out)
{
    __shared__ float buf[2 * 8 * ZONES];   // 2 batches x 8 rows x 128 cols = 8 KB

    const int tid  = threadIdx.x;
    const int rg   = blockIdx.x;           // row group 0..15 (rows rg*8 .. rg*8+7)
    const int b0   = blockIdx.y * NB;      // batch base

    const int boff = tid >> 7;             // which batch of the pair (0/1)
    const int t    = tid & 127;            // edge index within the row group
    const int e    = rg * 128 + t;         // global edge id
    const int srow = rg * 8 + (t >> 4);    // source zone (= output row)
    const int dcol = dst[e];               // destination zone (= output col)

    // Hoist this thread's edge weights into registers (reused for all batches).
    float w1[8], b1v[4], w2[16], b2v[4], w3[4];
    #pragma unroll
    for (int i = 0; i < 8; ++i)  w1[i]  = W1[e * 8 + i];
    #pragma unroll
    for (int i = 0; i < 4; ++i)  b1v[i] = b1[e * 4 + i];
    #pragma unroll
    for (int i = 0; i < 16; ++i) w2[i]  = W2[e * 16 + i];
    #pragma unroll
    for (int i = 0; i < 4; ++i)  b2v[i] = b2[e * 4 + i];
    #pragma unroll
    for (int i = 0; i < 4; ++i)  w3[i]  = W3[e * 4 + i];
    const float b3s = b3[e];

    float4* f4buf = reinterpret_cast<float4*>(buf);
    float4* out4  = reinterpret_cast<float4*>(out);
    const float4 ones4 = make_float4(1.f, 1.f, 1.f, 1.f);

    #pragma unroll
    for (int it = 0; it < NB / 2; ++it) {
        const int b = b0 + it * 2 + boff;

        // init LDS row buffers to 1.0 (512 float4 total, 2 per thread)
        f4buf[tid]       = ones4;
        f4buf[tid + 256] = ones4;
        __syncthreads();

        // gather pair features
        const float xs = x[b * ZONES + srow];
        const float xd = x[b * ZONES + dcol];

        // tiny MLP: 2 -> 4 -> 4 -> 1
        float h1[4];
        #pragma unroll
        for (int o = 0; o < 4; ++o)
            h1[o] = tanhf(fmaf(xs, w1[o], fmaf(xd, w1[4 + o], b1v[o])));

        float h2[4];
        #pragma unroll
        for (int o = 0; o < 4; ++o) {
            float z = b2v[o];
            #pragma unroll
            for (int k = 0; k < 4; ++k)
                z = fmaf(h1[k], w2[k * 4 + o], z);
            h2[o] = tanhf(z);
        }

        float z = b3s;
        #pragma unroll
        for (int o = 0; o < 4; ++o)
            z = fmaf(h2[o], w3[o], z);
        const float beta = 1.0f / (1.0f + __expf(-z));

        // scatter beta into its row (16 distinct cols per row -> no collisions)
        buf[boff * 1024 + (t >> 4) * 128 + dcol] = beta;
        __syncthreads();

        // coalesced store: per batch, 256 float4 = 8 rows x 128 floats
        #pragma unroll
        for (int bb = 0; bb < 2; ++bb) {
            const int bw = b0 + it * 2 + bb;
            out4[(size_t)bw * (ZONES * ZONES / 4) + rg * 256 + tid] =
                f4buf[bb * 256 + tid];
        }
        __syncthreads();   // protect LDS before next iteration's re-init
    }
}

extern "C" void kernel_launch(void* const* d_in, const int* in_sizes, int n_in,
                              void* d_out, int out_size, void* d_ws, size_t ws_size,
                              hipStream_t stream) {
    // setup_inputs order: x, dtPt, src, dst, W1, b1, W2, b2, W3, b3
    const float* x   = (const float*)d_in[0];
    const int*   dst = (const int*)  d_in[3];
    const float* W1  = (const float*)d_in[4];
    const float* b1  = (const float*)d_in[5];
    const float* W2  = (const float*)d_in[6];
    const float* b2  = (const float*)d_in[7];
    const float* W3  = (const float*)d_in[8];
    const float* b3  = (const float*)d_in[9];
    float* out = (float*)d_out;

    const int B = in_sizes[0] / ZONES;     // 4096
    dim3 grid(ZONES / 8, B / NB);          // (16, 512) = 8192 blocks
    fused_edge_mlp<<<grid, 256, 0, stream>>>(x, dst, W1, b1, W2, b2, W3, b3, out);
}

// Round 2
// 50.609 us; speedup vs baseline: 1.0162x; 1.0162x over previous
//
#include <hip/hip_runtime.h>

// B=4096, Z=128, DEG=16, E=2048. out[b,i,j]=1 except out[b,src[e],dst[e]]=beta[b,e].
// src[e]=e/16 (row-major edge grouping) -> row i owns edges [16i,16i+16).
//
// Key facts exploited:
//  * scatter POSITIONS are batch-independent -> init LDS ones ONCE, overwrite
//    the same 16 slots/row every batch (no per-iteration re-init).
//  * ping-pong parity buffers -> 1 barrier per iteration.
//  * per-thread edge weights (37 floats) hoisted to registers once, reused
//    for NB=32 batches.
//  * fast tanh/sigmoid via v_exp_f32 (|err|~1e-6, threshold 2e-2).

#define ZONES 128
#define NB    32   // batches per block

__device__ __forceinline__ float fast_tanh(float v) {
    // tanh(v) = 1 - 2/(exp(2v)+1)
    float e = __expf(2.0f * v);
    return 1.0f - 2.0f * __builtin_amdgcn_rcpf(e + 1.0f);
}
__device__ __forceinline__ float fast_sigmoid(float v) {
    return __builtin_amdgcn_rcpf(1.0f + __expf(-v));
}

__global__ __launch_bounds__(256) void fused_edge_mlp(
    const float* __restrict__ x,
    const int*   __restrict__ dst,
    const float* __restrict__ W1,
    const float* __restrict__ b1,
    const float* __restrict__ W2,
    const float* __restrict__ b2,
    const float* __restrict__ W3,
    const float* __restrict__ b3,
    float* __restrict__ out)
{
    // [parity][batch-half][8 rows * 128 cols] = 16 KB
    __shared__ float buf[2][2][8 * ZONES];

    const int tid  = threadIdx.x;
    const int rg   = blockIdx.x;          // row group: rows rg*8 .. rg*8+7
    const int b0   = blockIdx.y * NB;     // batch base

    const int boff = tid >> 7;            // 0/1: which batch of the pair
    const int t    = tid & 127;           // edge slot within row group
    const int e    = rg * 128 + t;        // global edge id
    const int srow = rg * 8 + (t >> 4);   // source zone (output row)
    const int dcol = dst[e];              // destination zone (output col)

    // hoist edge weights to registers (vectorized loads)
    float w1[8], b1v[4], w2[16], b2v[4], w3[4];
    *(float4*)&w1[0]  = ((const float4*)(W1 + e * 8))[0];
    *(float4*)&w1[4]  = ((const float4*)(W1 + e * 8))[1];
    *(float4*)&b1v[0] = ((const float4*)(b1 + e * 4))[0];
    *(float4*)&w2[0]  = ((const float4*)(W2 + e * 16))[0];
    *(float4*)&w2[4]  = ((const float4*)(W2 + e * 16))[1];
    *(float4*)&w2[8]  = ((const float4*)(W2 + e * 16))[2];
    *(float4*)&w2[12] = ((const float4*)(W2 + e * 16))[3];
    *(float4*)&b2v[0] = ((const float4*)(b2 + e * 4))[0];
    *(float4*)&w3[0]  = ((const float4*)(W3 + e * 4))[0];
    const float b3s = b3[e];

    // init ALL buffers to 1.0 exactly once; beta slots are batch-invariant
    float4* f4 = (float4*)buf;
    const float4 ones4 = make_float4(1.f, 1.f, 1.f, 1.f);
    #pragma unroll
    for (int i = 0; i < 4; ++i) f4[tid + 256 * i] = ones4;
    __syncthreads();

    float4* out4 = (float4*)out;
    const int scat = boff ? -1 : (t >> 4) * 128 + dcol;  // lane's fixed LDS slot

    #pragma unroll 4
    for (int it = 0; it < NB / 2; ++it) {
        const int p = it & 1;
        const int b = b0 + it * 2 + boff;

        const float xs = x[b * ZONES + srow];
        const float xd = x[b * ZONES + dcol];

        float h1[4];
        #pragma unroll
        for (int o = 0; o < 4; ++o)
            h1[o] = fast_tanh(fmaf(xs, w1[o], fmaf(xd, w1[4 + o], b1v[o])));

        float h2[4];
        #pragma unroll
        for (int o = 0; o < 4; ++o) {
            float z = b2v[o];
            #pragma unroll
            for (int k = 0; k < 4; ++k)
                z = fmaf(h1[k], w2[k * 4 + o], z);
            h2[o] = fast_tanh(z);
        }

        float z = b3s;
        #pragma unroll
        for (int o = 0; o < 4; ++o)
            z = fmaf(h2[o], w3[o], z);
        const float beta = fast_sigmoid(z);

        // scatter beta (16 distinct cols/row, positions fixed across batches)
        buf[p][boff][(t >> 4) * 128 + dcol] = beta;
        __syncthreads();

        // coalesced store of both batches' 8 rows (4 KB contiguous each)
        #pragma unroll
        for (int bb = 0; bb < 2; ++bb) {
            const int bw = b0 + it * 2 + bb;
            out4[(size_t)bw * (ZONES * ZONES / 4) + rg * 256 + tid] =
                ((float4*)buf[p][bb])[tid];
        }
        // no trailing barrier: next iter writes the OTHER parity buffer;
        // this parity is reused only after the next iteration's barrier.
    }
    (void)scat;
}

extern "C" void kernel_launch(void* const* d_in, const int* in_sizes, int n_in,
                              void* d_out, int out_size, void* d_ws, size_t ws_size,
                              hipStream_t stream) {
    // setup_inputs order: x, dtPt, src, dst, W1, b1, W2, b2, W3, b3
    const float* x   = (const float*)d_in[0];
    const int*   dst = (const int*)  d_in[3];
    const float* W1  = (const float*)d_in[4];
    const float* b1  = (const float*)d_in[5];
    const float* W2  = (const float*)d_in[6];
    const float* b2  = (const float*)d_in[7];
    const float* W3  = (const float*)d_in[8];
    const float* b3  = (const float*)d_in[9];
    float* out = (float*)d_out;

    const int B = in_sizes[0] / ZONES;     // 4096
    dim3 grid(ZONES / 8, B / NB);          // (16, 128) = 2048 blocks
    fused_edge_mlp<<<grid, 256, 0, stream>>>(x, dst, W1, b1, W2, b2, W3, b3, out);
}